// Round 13
// baseline (108.225 us; speedup 1.0000x reference)
//
#include <hip/hip_runtime.h>
#include <hip/hip_fp16.h>
#include <math.h>

static constexpr int N_NODES = 50000;
static constexpr int N_EDGES = 800000;
static constexpr int NFEAT = 512;
static constexpr int NHID = 96;
static constexpr int NCLASS = 40;
static constexpr int PREP_BLOCKS = 196;        // 196*256 = 50176 >= N_NODES
static constexpr int GEMM1_BLOCKS = (N_NODES + 127) / 128; // 391 (M-tile 128)
static constexpr int GEMM2_BLOCKS = (N_NODES + 63) / 64;   // 782
static constexpr int BUCKET = 64;              // max degree capacity (P(deg>63)~1e-13)
static constexpr int W2LD = 104;               // padded row stride (bf16)
// XCD-partitioned scatter geometry (R10-proven)
static constexpr int SC_GROUPS = 8;
static constexpr int SC_RANGE = N_NODES / SC_GROUPS;       // 6250
static constexpr int SC_CHUNK = 2048;
static constexpr int SC_CHUNKS = (N_EDGES + SC_CHUNK - 1) / SC_CHUNK;  // 391
static constexpr int SCATTER_BLOCKS = SC_GROUPS * SC_CHUNKS;           // 3128

typedef __bf16 bf16_t;
typedef __attribute__((ext_vector_type(8))) __bf16 bf16x8;
typedef __attribute__((ext_vector_type(4))) float f32x4;

// ---------------------------------------------------------------------------
// Zero-fill (fallback path only)
// ---------------------------------------------------------------------------
__global__ __launch_bounds__(256) void k_zero(int* __restrict__ p, int n) {
    int i = blockIdx.x * 256 + threadIdx.x;
    if (i < n) p[i] = 0;
}

// ---------------------------------------------------------------------------
// Prep (fused): W1 -> w1t bf16 transposed; W2 -> w2t bf16 transposed+padded;
// zero cnt[50000] (bucket cursors / degree counts).
// ---------------------------------------------------------------------------
__global__ __launch_bounds__(256) void k_prep(const float* __restrict__ W1,
                                              const float* __restrict__ W2,
                                              bf16_t* __restrict__ w1t,
                                              bf16_t* __restrict__ w2t,
                                              int* __restrict__ cnt) {
    int e = blockIdx.x * 256 + threadIdx.x;
    if (e < N_NODES) cnt[e] = 0;
    if (e < NFEAT * NHID) {
        int k = e / NHID;
        int n = e - k * NHID;
        w1t[(size_t)n * NFEAT + k] = (bf16_t)W1[e];
    }
    if (e < 48 * NHID) {
        int n = e / NHID;
        int k = e - n * NHID;
        w2t[n * W2LD + k] = (n < NCLASS) ? (bf16_t)W2[k * NCLASS + n] : (bf16_t)0.f;
    }
}

// ---------------------------------------------------------------------------
// FUSED GEMM1 (bf16 MFMA, M-tile=128) + XCD-partitioned scatter.
// R13 change vs R10 (one variable): gemm M-tile 64 -> 128 rows/block.
// - halves gemm blocks (782->391): total staging traffic, barrier count,
//   and w1t re-reads halve; MFMA per barrier pair doubles.
// - each B-fragment ds_read is shared by TWO row-sets (half ds_read/MFMA).
// R12's x-prefetch was NULL (x latency already TLP-hidden) -> R10's proven
// in-loop load placement kept. Proven 128B-stride swizzle kept (R11 lesson).
// Scatter path unchanged (R10-proven).
// ---------------------------------------------------------------------------
static __device__ inline bf16x8 cvt8(float4 u, float4 v) {
    bf16x8 r;
    r[0] = (bf16_t)u.x; r[1] = (bf16_t)u.y; r[2] = (bf16_t)u.z; r[3] = (bf16_t)u.w;
    r[4] = (bf16_t)v.x; r[5] = (bf16_t)v.y; r[6] = (bf16_t)v.z; r[7] = (bf16_t)v.w;
    return r;
}

__global__ __launch_bounds__(256) void k_gemm1_scatter(
        const float* __restrict__ x, const bf16_t* __restrict__ w1t,
        const float* __restrict__ b1, bf16_t* __restrict__ support,
        const int* __restrict__ src, const int* __restrict__ dst,
        const float* __restrict__ ew, int* __restrict__ cnt,
        unsigned int* __restrict__ buck) {
    __shared__ bf16_t Bs[NHID * 64];  // [n][k] 96x64 bf16 = 12KB, XOR-swizzled
    const int tid = threadIdx.x;

    if (blockIdx.x >= GEMM1_BLOCKS) {  // scatter path (block-uniform branch)
        const int si = blockIdx.x - GEMM1_BLOCKS;
        const int g = si & 7;           // dst-range group == XCD-coherent set
        const int c = si >> 3;          // edge chunk
        const int lo = g * SC_RANGE;
        const int hi = lo + SC_RANGE;
        const int base = c * SC_CHUNK;
#pragma unroll
        for (int t = 0; t < SC_CHUNK / 256; ++t) {
            int i = base + t * 256 + tid;
            if (i < N_EDGES) {
                int d = dst[i];
                if (d >= lo && d < hi) {
                    int rank = atomicAdd(&cnt[d], 1);
                    if (rank < BUCKET) {
                        __half hh = __float2half(ew[i]);
                        unsigned short us = *reinterpret_cast<unsigned short*>(&hh);
                        buck[(size_t)d * BUCKET + rank] =
                            ((unsigned int)src[i] << 16) | (unsigned int)us;
                    }
                }
            }
        }
        return;
    }

    const int w = tid >> 6;
    const int l = tid & 63;
    const int row0 = blockIdx.x * 128;

    int arow0 = row0 + w * 32 + (l & 15);
    int arow1 = arow0 + 16;
    if (arow0 > N_NODES - 1) arow0 = N_NODES - 1;  // clamp: dup loads, masked store
    if (arow1 > N_NODES - 1) arow1 = N_NODES - 1;
    const float* ap0 = x + (size_t)arow0 * NFEAT + ((l >> 4) << 3);
    const float* ap1 = x + (size_t)arow1 * NFEAT + ((l >> 4) << 3);

    f32x4 acc[2][6];
#pragma unroll
    for (int rt = 0; rt < 2; ++rt)
#pragma unroll
        for (int nt = 0; nt < 6; ++nt) acc[rt][nt] = (f32x4){0.f, 0.f, 0.f, 0.f};

    const int koff = (l >> 4) << 4;  // kq*16 bytes

    for (int kt = 0; kt < NFEAT; kt += 64) {
        // A loads for both row-sets (issue early; drain at first barrier)
        float4 a0 = *reinterpret_cast<const float4*>(ap0 + kt);
        float4 a1 = *reinterpret_cast<const float4*>(ap0 + kt + 4);
        float4 a2 = *reinterpret_cast<const float4*>(ap0 + kt + 32);
        float4 a3 = *reinterpret_cast<const float4*>(ap0 + kt + 36);
        float4 a4 = *reinterpret_cast<const float4*>(ap1 + kt);
        float4 a5 = *reinterpret_cast<const float4*>(ap1 + kt + 4);
        float4 a6 = *reinterpret_cast<const float4*>(ap1 + kt + 32);
        float4 a7 = *reinterpret_cast<const float4*>(ap1 + kt + 36);

        __syncthreads();  // previous tile's B reads complete
        // stage B tile [96][64]: proven swizzle, both sides
#pragma unroll
        for (int p = 0; p < 3; ++p) {
            int idx = tid + p * 256;
            int n = idx >> 3;
            int c4 = idx & 7;
            uint4 v = *reinterpret_cast<const uint4*>(w1t + (size_t)n * NFEAT + kt + c4 * 8);
            int ba = (n * 128 + c4 * 16) ^ ((n & 7) << 4);
            *reinterpret_cast<uint4*>(reinterpret_cast<char*>(Bs) + ba) = v;
        }
        __syncthreads();

        bf16x8 af0 = cvt8(a0, a1);
        bf16x8 af1 = cvt8(a2, a3);
        bf16x8 af2 = cvt8(a4, a5);
        bf16x8 af3 = cvt8(a6, a7);
#pragma unroll
        for (int nt = 0; nt < 6; ++nt) {
            int n = nt * 16 + (l & 15);
            int ba0 = (n * 128 + koff) ^ ((n & 7) << 4);
            int ba1 = (n * 128 + 64 + koff) ^ ((n & 7) << 4);
            bf16x8 bf0 = *reinterpret_cast<const bf16x8*>(reinterpret_cast<const char*>(Bs) + ba0);
            bf16x8 bf1 = *reinterpret_cast<const bf16x8*>(reinterpret_cast<const char*>(Bs) + ba1);
            // B-fragments shared across both row-sets
            acc[0][nt] = __builtin_amdgcn_mfma_f32_16x16x32_bf16(af0, bf0, acc[0][nt], 0, 0, 0);
            acc[0][nt] = __builtin_amdgcn_mfma_f32_16x16x32_bf16(af1, bf1, acc[0][nt], 0, 0, 0);
            acc[1][nt] = __builtin_amdgcn_mfma_f32_16x16x32_bf16(af2, bf0, acc[1][nt], 0, 0, 0);
            acc[1][nt] = __builtin_amdgcn_mfma_f32_16x16x32_bf16(af3, bf1, acc[1][nt], 0, 0, 0);
        }
    }

    // Epilogue: C layout col=lane&15, row=(lane>>4)*4+reg (m89-verified)
    const int col16 = l & 15;
    const int rq = l >> 4;
#pragma unroll
    for (int rt = 0; rt < 2; ++rt) {
#pragma unroll
        for (int nt = 0; nt < 6; ++nt) {
            int col = nt * 16 + col16;
            float bv = b1[col];
#pragma unroll
            for (int r = 0; r < 4; ++r) {
                int row = row0 + w * 32 + rt * 16 + rq * 4 + r;
                if (row < N_NODES)
                    support[(size_t)row * NHID + col] = (bf16_t)(acc[rt][nt][r] + bv);
            }
        }
    }
}

// ---------------------------------------------------------------------------
// Pull-mode aggregate + ReLU from padded buckets (R8-proven).
// ---------------------------------------------------------------------------
static __device__ inline float dec_w(unsigned int v) {
    unsigned short us = (unsigned short)(v & 0xffffu);
    __half hh = *reinterpret_cast<__half*>(&us);
    return __half2float(hh);
}

__global__ __launch_bounds__(256) void k_agg(const bf16_t* __restrict__ support,
                                             const int* __restrict__ cnt,
                                             const unsigned int* __restrict__ buck,
                                             bf16_t* __restrict__ h) {
    const int g = blockIdx.x * 8 + (threadIdx.x >> 5);
    const int l = threadIdx.x & 31;
    if (g >= N_NODES) return;
    int deg = cnt[g];
    if (deg > BUCKET) deg = BUCKET;  // safety clamp (stat. unreachable)
    const unsigned int* bk = buck + (size_t)g * BUCKET;
    float a0 = 0.f, a1 = 0.f, a2 = 0.f;
    int e = 0;
    for (; e + 4 <= deg; e += 4) {
        uint4 q = *reinterpret_cast<const uint4*>(bk + e);
        const bf16_t* r0 = support + (size_t)(q.x >> 16) * NHID;
        const bf16_t* r1 = support + (size_t)(q.y >> 16) * NHID;
        const bf16_t* r2 = support + (size_t)(q.z >> 16) * NHID;
        const bf16_t* r3 = support + (size_t)(q.w >> 16) * NHID;
        float w0 = dec_w(q.x), w1 = dec_w(q.y), w2 = dec_w(q.z), w3 = dec_w(q.w);
        float v00 = (float)r0[l], v01 = (float)r0[l + 32], v02 = (float)r0[l + 64];
        float v10 = (float)r1[l], v11 = (float)r1[l + 32], v12 = (float)r1[l + 64];
        float v20 = (float)r2[l], v21 = (float)r2[l + 32], v22 = (float)r2[l + 64];
        float v30 = (float)r3[l], v31 = (float)r3[l + 32], v32 = (float)r3[l + 64];
        a0 = fmaf(w0, v00, a0); a1 = fmaf(w0, v01, a1); a2 = fmaf(w0, v02, a2);
        a0 = fmaf(w1, v10, a0); a1 = fmaf(w1, v11, a1); a2 = fmaf(w1, v12, a2);
        a0 = fmaf(w2, v20, a0); a1 = fmaf(w2, v21, a1); a2 = fmaf(w2, v22, a2);
        a0 = fmaf(w3, v30, a0); a1 = fmaf(w3, v31, a1); a2 = fmaf(w3, v32, a2);
    }
    for (; e < deg; ++e) {
        unsigned int v = bk[e];
        const bf16_t* r = support + (size_t)(v >> 16) * NHID;
        float wv = dec_w(v);
        a0 = fmaf(wv, (float)r[l], a0);
        a1 = fmaf(wv, (float)r[l + 32], a1);
        a2 = fmaf(wv, (float)r[l + 64], a2);
    }
    bf16_t* hr = h + (size_t)g * NHID;
    hr[l]      = (bf16_t)fmaxf(a0, 0.f);
    hr[l + 32] = (bf16_t)fmaxf(a1, 0.f);
    hr[l + 64] = (bf16_t)fmaxf(a2, 0.f);
}

// ---------------------------------------------------------------------------
// GEMM2 (bf16 MFMA) + bias + log_softmax fused (R4-proven).
// ---------------------------------------------------------------------------
__global__ __launch_bounds__(256) void k_gemm2_mfma(const bf16_t* __restrict__ h,
                                                    const bf16_t* __restrict__ w2t,
                                                    const float* __restrict__ b2,
                                                    float* __restrict__ out) {
    __shared__ bf16_t Bs[48 * W2LD];
    const int tid = threadIdx.x;
#pragma unroll
    for (int i = tid; i < 48 * W2LD / 8; i += 256)
        *reinterpret_cast<uint4*>(Bs + i * 8) =
            *reinterpret_cast<const uint4*>(w2t + i * 8);

    const int w = tid >> 6;
    const int l = tid & 63;
    const int row0 = blockIdx.x * 64 + w * 16;
    int arow = row0 + (l & 15);
    if (arow > N_NODES - 1) arow = N_NODES - 1;
    const bf16_t* ap = h + (size_t)arow * NHID + ((l >> 4) << 3);

    f32x4 acc[3];
#pragma unroll
    for (int nt = 0; nt < 3; ++nt) acc[nt] = (f32x4){0.f, 0.f, 0.f, 0.f};
    __syncthreads();

#pragma unroll
    for (int ks = 0; ks < 3; ++ks) {
        bf16x8 af = *reinterpret_cast<const bf16x8*>(ap + ks * 32);
#pragma unroll
        for (int nt = 0; nt < 3; ++nt) {
            int n = nt * 16 + (l & 15);
            bf16x8 bf = *reinterpret_cast<const bf16x8*>(
                &Bs[n * W2LD + ks * 32 + ((l >> 4) << 3)]);
            acc[nt] = __builtin_amdgcn_mfma_f32_16x16x32_bf16(af, bf, acc[nt], 0, 0, 0);
        }
    }

    const int c16 = l & 15;
    float bv[3];
    bool val[3];
#pragma unroll
    for (int nt = 0; nt < 3; ++nt) {
        int col = nt * 16 + c16;
        val[nt] = col < NCLASS;
        bv[nt] = val[nt] ? b2[col] : 0.f;
    }
#pragma unroll
    for (int r = 0; r < 4; ++r) {
        float lg[3];
        float m = -1e30f;
#pragma unroll
        for (int nt = 0; nt < 3; ++nt) {
            lg[nt] = acc[nt][r] + bv[nt];
            if (val[nt]) m = fmaxf(m, lg[nt]);
        }
#pragma unroll
        for (int off = 1; off < 16; off <<= 1) m = fmaxf(m, __shfl_xor(m, off));
        float s = 0.f;
#pragma unroll
        for (int nt = 0; nt < 3; ++nt)
            if (val[nt]) s += __expf(lg[nt] - m);
#pragma unroll
        for (int off = 1; off < 16; off <<= 1) s += __shfl_xor(s, off);
        float lse = __logf(s);
        int row = row0 + ((l >> 4) << 2) + r;
        if (row < N_NODES) {
#pragma unroll
            for (int nt = 0; nt < 3; ++nt)
                if (val[nt])
                    out[(size_t)row * NCLASS + nt * 16 + c16] = lg[nt] - m - lse;
        }
    }
}

// ---------------------------------------------------------------------------
// Fallback path (workspace too small for buckets)
// ---------------------------------------------------------------------------
__global__ __launch_bounds__(256) void k_agg_atomic(const bf16_t* __restrict__ support,
                                                    const int* __restrict__ src,
                                                    const int* __restrict__ dst,
                                                    const float* __restrict__ ew,
                                                    float* __restrict__ hf) {
    int e = blockIdx.x * 8 + (threadIdx.x >> 5);
    int l = threadIdx.x & 31;
    if (e >= N_EDGES) return;
    int s = src[e];
    int d = dst[e];
    float w = ew[e];
    const bf16_t* r = support + (size_t)s * NHID;
    float* hd = hf + (size_t)d * NHID;
    atomicAdd(&hd[l], w * (float)r[l]);
    atomicAdd(&hd[l + 32], w * (float)r[l + 32]);
    atomicAdd(&hd[l + 64], w * (float)r[l + 64]);
}

__global__ __launch_bounds__(256) void k_gemm2_fb(const float* __restrict__ hf,
                                                  const bf16_t* __restrict__ w2t,
                                                  const float* __restrict__ b2,
                                                  float* __restrict__ out) {
    __shared__ bf16_t hs[64][W2LD];
    __shared__ bf16_t Bs[48 * W2LD];
    const int tid = threadIdx.x;
#pragma unroll
    for (int i = tid; i < 48 * W2LD / 8; i += 256)
        *reinterpret_cast<uint4*>(Bs + i * 8) =
            *reinterpret_cast<const uint4*>(w2t + i * 8);
    const int row0 = blockIdx.x * 64;
    for (int i = tid; i < 64 * NHID; i += 256) {
        int r = i / NHID, c = i - r * NHID;
        int row = row0 + r;
        float v = (row < N_NODES) ? fmaxf(hf[(size_t)row * NHID + c], 0.f) : 0.f;
        hs[r][c] = (bf16_t)v;
    }
    __syncthreads();
    const int w = tid >> 6;
    const int l64 = tid & 63;
    const int r16 = l64 & 15;
    const int kq = l64 >> 4;
    f32x4 acc[3];
#pragma unroll
    for (int nt = 0; nt < 3; ++nt) acc[nt] = (f32x4){0.f, 0.f, 0.f, 0.f};
#pragma unroll
    for (int ks = 0; ks < 3; ++ks) {
        bf16x8 af = *reinterpret_cast<const bf16x8*>(&hs[w * 16 + r16][ks * 32 + (kq << 3)]);
#pragma unroll
        for (int nt = 0; nt < 3; ++nt) {
            int n = nt * 16 + r16;
            bf16x8 bf = *reinterpret_cast<const bf16x8*>(&Bs[n * W2LD + ks * 32 + (kq << 3)]);
            acc[nt] = __builtin_amdgcn_mfma_f32_16x16x32_bf16(af, bf, acc[nt], 0, 0, 0);
        }
    }
    float bv[3];
    bool val[3];
#pragma unroll
    for (int nt = 0; nt < 3; ++nt) {
        int col = nt * 16 + r16;
        val[nt] = col < NCLASS;
        bv[nt] = val[nt] ? b2[col] : 0.f;
    }
#pragma unroll
    for (int r = 0; r < 4; ++r) {
        float lg[3];
        float m = -1e30f;
#pragma unroll
        for (int nt = 0; nt < 3; ++nt) {
            lg[nt] = acc[nt][r] + bv[nt];
            if (val[nt]) m = fmaxf(m, lg[nt]);
        }
#pragma unroll
        for (int off = 1; off < 16; off <<= 1) m = fmaxf(m, __shfl_xor(m, off));
        float s = 0.f;
#pragma unroll
        for (int nt = 0; nt < 3; ++nt)
            if (val[nt]) s += __expf(lg[nt] - m);
#pragma unroll
        for (int off = 1; off < 16; off <<= 1) s += __shfl_xor(s, off);
        float lse = __logf(s);
        int row = row0 + w * 16 + kq * 4 + r;
        if (row < N_NODES) {
#pragma unroll
            for (int nt = 0; nt < 3; ++nt)
                if (val[nt])
                    out[(size_t)row * NCLASS + nt * 16 + r16] = lg[nt] - m - lse;
        }
    }
}

// ---------------------------------------------------------------------------
extern "C" void kernel_launch(void* const* d_in, const int* in_sizes, int n_in,
                              void* d_out, int out_size, void* d_ws, size_t ws_size,
                              hipStream_t stream) {
    const float* x  = (const float*)d_in[0];
    const int* ei   = (const int*)d_in[1];
    const float* ew = (const float*)d_in[2];
    const float* W1 = (const float*)d_in[3];
    const float* b1 = (const float*)d_in[4];
    const float* W2 = (const float*)d_in[5];
    const float* b2 = (const float*)d_in[6];
    float* out = (float*)d_out;
    const int* src = ei;
    const int* dst = ei + N_EDGES;

    char* ws = (char*)d_ws;
    size_t off = 0;
    auto alloc = [&](size_t bytes) -> void* {
        void* p = ws + off;
        off = (off + bytes + 255) & ~(size_t)255;
        return p;
    };
    bf16_t* support = (bf16_t*)alloc((size_t)N_NODES * NHID * 2);
    bf16_t* h       = (bf16_t*)alloc((size_t)N_NODES * NHID * 2);
    bf16_t* w1t     = (bf16_t*)alloc((size_t)NHID * NFEAT * 2);
    bf16_t* w2t     = (bf16_t*)alloc((size_t)48 * W2LD * 2);
    int* cnt        = (int*)alloc((size_t)N_NODES * 4);
    unsigned int* buck = (unsigned int*)alloc((size_t)N_NODES * BUCKET * 4);
    const bool fits = (off <= ws_size);
    float* hf       = (float*)alloc((size_t)N_NODES * NHID * 4);  // fallback only

    k_prep<<<PREP_BLOCKS, 256, 0, stream>>>(W1, W2, w1t, w2t, cnt);

    if (fits) {
        k_gemm1_scatter<<<GEMM1_BLOCKS + SCATTER_BLOCKS, 256, 0, stream>>>(
            x, w1t, b1, support, src, dst, ew, cnt, buck);
        k_agg<<<(N_NODES + 7) / 8, 256, 0, stream>>>(support, cnt, buck, h);
        k_gemm2_mfma<<<GEMM2_BLOCKS, 256, 0, stream>>>(h, w2t, b2, out);
    } else {
        k_gemm1_scatter<<<GEMM1_BLOCKS, 256, 0, stream>>>(
            x, w1t, b1, support, src, dst, ew, cnt, buck);
        k_zero<<<(N_NODES * NHID + 255) / 256, 256, 0, stream>>>((int*)hf, N_NODES * NHID);
        k_agg_atomic<<<(N_EDGES + 7) / 8, 256, 0, stream>>>(support, src, dst, ew, hf);
        k_gemm2_fb<<<GEMM2_BLOCKS, 256, 0, stream>>>(hf, w2t, b2, out);
    }
}

// Round 14
// 100.278 us; speedup vs baseline: 1.0793x; 1.0793x over previous
//
#include <hip/hip_runtime.h>
#include <hip/hip_fp16.h>
#include <math.h>

static constexpr int N_NODES = 50000;
static constexpr int N_EDGES = 800000;
static constexpr int NFEAT = 512;
static constexpr int NHID = 96;
static constexpr int NCLASS = 40;
static constexpr int PREP_BLOCKS = 196;        // 196*256 = 50176 >= N_NODES
static constexpr int GEMM1_BLOCKS = (N_NODES + 63) / 64;   // 782 (R10-proven)
static constexpr int BUCKET = 64;              // max degree capacity (P(deg>63)~1e-13)
static constexpr int W2LD = 104;               // padded row stride (bf16)
// XCD-partitioned scatter geometry (R10-proven)
static constexpr int SC_GROUPS = 8;
static constexpr int SC_RANGE = N_NODES / SC_GROUPS;       // 6250
static constexpr int SC_CHUNK = 2048;
static constexpr int SC_CHUNKS = (N_EDGES + SC_CHUNK - 1) / SC_CHUNK;  // 391
static constexpr int SCATTER_BLOCKS = SC_GROUPS * SC_CHUNKS;           // 3128

typedef __bf16 bf16_t;
typedef __attribute__((ext_vector_type(8))) __bf16 bf16x8;
typedef __attribute__((ext_vector_type(4))) float f32x4;

// ---------------------------------------------------------------------------
// Zero-fill (fallback path only)
// ---------------------------------------------------------------------------
__global__ __launch_bounds__(256) void k_zero(int* __restrict__ p, int n) {
    int i = blockIdx.x * 256 + threadIdx.x;
    if (i < n) p[i] = 0;
}

// ---------------------------------------------------------------------------
// Prep (fused): W1 -> w1t bf16 transposed; W2 -> w2t bf16 transposed+padded;
// zero cnt[50000] (bucket cursors / degree counts).
// ---------------------------------------------------------------------------
__global__ __launch_bounds__(256) void k_prep(const float* __restrict__ W1,
                                              const float* __restrict__ W2,
                                              bf16_t* __restrict__ w1t,
                                              bf16_t* __restrict__ w2t,
                                              int* __restrict__ cnt) {
    int e = blockIdx.x * 256 + threadIdx.x;
    if (e < N_NODES) cnt[e] = 0;
    if (e < NFEAT * NHID) {
        int k = e / NHID;
        int n = e - k * NHID;
        w1t[(size_t)n * NFEAT + k] = (bf16_t)W1[e];
    }
    if (e < 48 * NHID) {
        int n = e / NHID;
        int k = e - n * NHID;
        w2t[n * W2LD + k] = (n < NCLASS) ? (bf16_t)W2[k * NCLASS + n] : (bf16_t)0.f;
    }
}

// ---------------------------------------------------------------------------
// FUSED GEMM1 (bf16 MFMA) + XCD-partitioned scatter -- EXACT R10 body
// (proven best: 103.1us total). Gemm-side probes all regressed or null:
// R9 no-LDS (worse), R11 256B-chunk (bank conflicts), R12 x-prefetch (null),
// R13 M-tile 128 (worse). This config is the empirical local optimum.
// ---------------------------------------------------------------------------
static __device__ inline bf16x8 cvt8(float4 u, float4 v) {
    bf16x8 r;
    r[0] = (bf16_t)u.x; r[1] = (bf16_t)u.y; r[2] = (bf16_t)u.z; r[3] = (bf16_t)u.w;
    r[4] = (bf16_t)v.x; r[5] = (bf16_t)v.y; r[6] = (bf16_t)v.z; r[7] = (bf16_t)v.w;
    return r;
}

__global__ __launch_bounds__(256) void k_gemm1_scatter(
        const float* __restrict__ x, const bf16_t* __restrict__ w1t,
        const float* __restrict__ b1, bf16_t* __restrict__ support,
        const int* __restrict__ src, const int* __restrict__ dst,
        const float* __restrict__ ew, int* __restrict__ cnt,
        unsigned int* __restrict__ buck) {
    __shared__ bf16_t Bs[NHID * 64];  // [n][k] 96x64 bf16 = 12KB, XOR-swizzled
    const int tid = threadIdx.x;

    if (blockIdx.x >= GEMM1_BLOCKS) {  // scatter path (block-uniform branch)
        const int si = blockIdx.x - GEMM1_BLOCKS;
        const int g = si & 7;           // dst-range group == XCD-coherent set
        const int c = si >> 3;          // edge chunk
        const int lo = g * SC_RANGE;
        const int hi = lo + SC_RANGE;
        const int base = c * SC_CHUNK;
#pragma unroll
        for (int t = 0; t < SC_CHUNK / 256; ++t) {
            int i = base + t * 256 + tid;
            if (i < N_EDGES) {
                int d = dst[i];
                if (d >= lo && d < hi) {
                    int rank = atomicAdd(&cnt[d], 1);
                    if (rank < BUCKET) {
                        __half hh = __float2half(ew[i]);
                        unsigned short us = *reinterpret_cast<unsigned short*>(&hh);
                        buck[(size_t)d * BUCKET + rank] =
                            ((unsigned int)src[i] << 16) | (unsigned int)us;
                    }
                }
            }
        }
        return;
    }

    const int w = tid >> 6;
    const int l = tid & 63;
    const int row0 = blockIdx.x * 64;

    int arow = row0 + w * 16 + (l & 15);
    if (arow > N_NODES - 1) arow = N_NODES - 1;  // clamp: dup loads, masked store
    const float* ap = x + (size_t)arow * NFEAT + ((l >> 4) << 3);

    f32x4 acc[6];
#pragma unroll
    for (int nt = 0; nt < 6; ++nt) acc[nt] = (f32x4){0.f, 0.f, 0.f, 0.f};

    for (int kt = 0; kt < NFEAT; kt += 64) {
        float4 a0 = *reinterpret_cast<const float4*>(ap + kt);
        float4 a1 = *reinterpret_cast<const float4*>(ap + kt + 4);
        float4 a2 = *reinterpret_cast<const float4*>(ap + kt + 32);
        float4 a3 = *reinterpret_cast<const float4*>(ap + kt + 36);

        __syncthreads();
#pragma unroll
        for (int p = 0; p < 3; ++p) {
            int idx = tid + p * 256;
            int n = idx >> 3;
            int c4 = idx & 7;
            uint4 v = *reinterpret_cast<const uint4*>(w1t + (size_t)n * NFEAT + kt + c4 * 8);
            int ba = (n * 128 + c4 * 16) ^ ((n & 7) << 4);
            *reinterpret_cast<uint4*>(reinterpret_cast<char*>(Bs) + ba) = v;
        }
        __syncthreads();

        bf16x8 af0 = cvt8(a0, a1);
        bf16x8 af1 = cvt8(a2, a3);
        const int koff = (l >> 4) << 4;
#pragma unroll
        for (int nt = 0; nt < 6; ++nt) {
            int n = nt * 16 + (l & 15);
            int ba0 = (n * 128 + koff) ^ ((n & 7) << 4);
            int ba1 = (n * 128 + 64 + koff) ^ ((n & 7) << 4);
            bf16x8 bf0 = *reinterpret_cast<const bf16x8*>(reinterpret_cast<const char*>(Bs) + ba0);
            bf16x8 bf1 = *reinterpret_cast<const bf16x8*>(reinterpret_cast<const char*>(Bs) + ba1);
            acc[nt] = __builtin_amdgcn_mfma_f32_16x16x32_bf16(af0, bf0, acc[nt], 0, 0, 0);
            acc[nt] = __builtin_amdgcn_mfma_f32_16x16x32_bf16(af1, bf1, acc[nt], 0, 0, 0);
        }
    }

    // Epilogue: C layout col=lane&15, row=(lane>>4)*4+reg (m89-verified)
    const int col16 = l & 15;
    const int rq = l >> 4;
#pragma unroll
    for (int nt = 0; nt < 6; ++nt) {
        int col = nt * 16 + col16;
        float bv = b1[col];
#pragma unroll
        for (int r = 0; r < 4; ++r) {
            int row = row0 + w * 16 + rq * 4 + r;
            if (row < N_NODES)
                support[(size_t)row * NHID + col] = (bf16_t)(acc[nt][r] + bv);
        }
    }
}

// ---------------------------------------------------------------------------
// Pull-mode aggregate + ReLU from padded buckets.
// R14 change (one variable): 8-edge unroll -> 24 support-gathers in flight
// per 32-lane group (was 12). Avg deg 16: serial gather rounds 4 -> 2.
// Targets the latency-bound regime of the L2/L3 gather (154MB logical).
// ---------------------------------------------------------------------------
static __device__ inline float dec_w(unsigned int v) {
    unsigned short us = (unsigned short)(v & 0xffffu);
    __half hh = *reinterpret_cast<__half*>(&us);
    return __half2float(hh);
}

__global__ __launch_bounds__(256) void k_agg(const bf16_t* __restrict__ support,
                                             const int* __restrict__ cnt,
                                             const unsigned int* __restrict__ buck,
                                             bf16_t* __restrict__ h) {
    const int g = blockIdx.x * 8 + (threadIdx.x >> 5);
    const int l = threadIdx.x & 31;
    if (g >= N_NODES) return;
    int deg = cnt[g];
    if (deg > BUCKET) deg = BUCKET;  // safety clamp (stat. unreachable)
    const unsigned int* bk = buck + (size_t)g * BUCKET;
    float a0 = 0.f, a1 = 0.f, a2 = 0.f;
    int e = 0;
    for (; e + 8 <= deg; e += 8) {
        uint4 q = *reinterpret_cast<const uint4*>(bk + e);
        uint4 p = *reinterpret_cast<const uint4*>(bk + e + 4);
        const bf16_t* r0 = support + (size_t)(q.x >> 16) * NHID;
        const bf16_t* r1 = support + (size_t)(q.y >> 16) * NHID;
        const bf16_t* r2 = support + (size_t)(q.z >> 16) * NHID;
        const bf16_t* r3 = support + (size_t)(q.w >> 16) * NHID;
        const bf16_t* r4 = support + (size_t)(p.x >> 16) * NHID;
        const bf16_t* r5 = support + (size_t)(p.y >> 16) * NHID;
        const bf16_t* r6 = support + (size_t)(p.z >> 16) * NHID;
        const bf16_t* r7 = support + (size_t)(p.w >> 16) * NHID;
        float w0 = dec_w(q.x), w1 = dec_w(q.y), w2 = dec_w(q.z), w3 = dec_w(q.w);
        float w4 = dec_w(p.x), w5 = dec_w(p.y), w6 = dec_w(p.z), w7 = dec_w(p.w);
        // 24 gathers issued before the FMA block
        float v00 = (float)r0[l], v01 = (float)r0[l + 32], v02 = (float)r0[l + 64];
        float v10 = (float)r1[l], v11 = (float)r1[l + 32], v12 = (float)r1[l + 64];
        float v20 = (float)r2[l], v21 = (float)r2[l + 32], v22 = (float)r2[l + 64];
        float v30 = (float)r3[l], v31 = (float)r3[l + 32], v32 = (float)r3[l + 64];
        float v40 = (float)r4[l], v41 = (float)r4[l + 32], v42 = (float)r4[l + 64];
        float v50 = (float)r5[l], v51 = (float)r5[l + 32], v52 = (float)r5[l + 64];
        float v60 = (float)r6[l], v61 = (float)r6[l + 32], v62 = (float)r6[l + 64];
        float v70 = (float)r7[l], v71 = (float)r7[l + 32], v72 = (float)r7[l + 64];
        a0 = fmaf(w0, v00, a0); a1 = fmaf(w0, v01, a1); a2 = fmaf(w0, v02, a2);
        a0 = fmaf(w1, v10, a0); a1 = fmaf(w1, v11, a1); a2 = fmaf(w1, v12, a2);
        a0 = fmaf(w2, v20, a0); a1 = fmaf(w2, v21, a1); a2 = fmaf(w2, v22, a2);
        a0 = fmaf(w3, v30, a0); a1 = fmaf(w3, v31, a1); a2 = fmaf(w3, v32, a2);
        a0 = fmaf(w4, v40, a0); a1 = fmaf(w4, v41, a1); a2 = fmaf(w4, v42, a2);
        a0 = fmaf(w5, v50, a0); a1 = fmaf(w5, v51, a1); a2 = fmaf(w5, v52, a2);
        a0 = fmaf(w6, v60, a0); a1 = fmaf(w6, v61, a1); a2 = fmaf(w6, v62, a2);
        a0 = fmaf(w7, v70, a0); a1 = fmaf(w7, v71, a1); a2 = fmaf(w7, v72, a2);
    }
    for (; e + 4 <= deg; e += 4) {
        uint4 q = *reinterpret_cast<const uint4*>(bk + e);
        const bf16_t* r0 = support + (size_t)(q.x >> 16) * NHID;
        const bf16_t* r1 = support + (size_t)(q.y >> 16) * NHID;
        const bf16_t* r2 = support + (size_t)(q.z >> 16) * NHID;
        const bf16_t* r3 = support + (size_t)(q.w >> 16) * NHID;
        float w0 = dec_w(q.x), w1 = dec_w(q.y), w2 = dec_w(q.z), w3 = dec_w(q.w);
        float v00 = (float)r0[l], v01 = (float)r0[l + 32], v02 = (float)r0[l + 64];
        float v10 = (float)r1[l], v11 = (float)r1[l + 32], v12 = (float)r1[l + 64];
        float v20 = (float)r2[l], v21 = (float)r2[l + 32], v22 = (float)r2[l + 64];
        float v30 = (float)r3[l], v31 = (float)r3[l + 32], v32 = (float)r3[l + 64];
        a0 = fmaf(w0, v00, a0); a1 = fmaf(w0, v01, a1); a2 = fmaf(w0, v02, a2);
        a0 = fmaf(w1, v10, a0); a1 = fmaf(w1, v11, a1); a2 = fmaf(w1, v12, a2);
        a0 = fmaf(w2, v20, a0); a1 = fmaf(w2, v21, a1); a2 = fmaf(w2, v22, a2);
        a0 = fmaf(w3, v30, a0); a1 = fmaf(w3, v31, a1); a2 = fmaf(w3, v32, a2);
    }
    for (; e < deg; ++e) {
        unsigned int v = bk[e];
        const bf16_t* r = support + (size_t)(v >> 16) * NHID;
        float wv = dec_w(v);
        a0 = fmaf(wv, (float)r[l], a0);
        a1 = fmaf(wv, (float)r[l + 32], a1);
        a2 = fmaf(wv, (float)r[l + 64], a2);
    }
    bf16_t* hr = h + (size_t)g * NHID;
    hr[l]      = (bf16_t)fmaxf(a0, 0.f);
    hr[l + 32] = (bf16_t)fmaxf(a1, 0.f);
    hr[l + 64] = (bf16_t)fmaxf(a2, 0.f);
}

// ---------------------------------------------------------------------------
// GEMM2 (bf16 MFMA) + bias + log_softmax fused (R4-proven).
// ---------------------------------------------------------------------------
__global__ __launch_bounds__(256) void k_gemm2_mfma(const bf16_t* __restrict__ h,
                                                    const bf16_t* __restrict__ w2t,
                                                    const float* __restrict__ b2,
                                                    float* __restrict__ out) {
    __shared__ bf16_t Bs[48 * W2LD];
    const int tid = threadIdx.x;
#pragma unroll
    for (int i = tid; i < 48 * W2LD / 8; i += 256)
        *reinterpret_cast<uint4*>(Bs + i * 8) =
            *reinterpret_cast<const uint4*>(w2t + i * 8);

    const int w = tid >> 6;
    const int l = tid & 63;
    const int row0 = blockIdx.x * 64 + w * 16;
    int arow = row0 + (l & 15);
    if (arow > N_NODES - 1) arow = N_NODES - 1;
    const bf16_t* ap = h + (size_t)arow * NHID + ((l >> 4) << 3);

    f32x4 acc[3];
#pragma unroll
    for (int nt = 0; nt < 3; ++nt) acc[nt] = (f32x4){0.f, 0.f, 0.f, 0.f};
    __syncthreads();

#pragma unroll
    for (int ks = 0; ks < 3; ++ks) {
        bf16x8 af = *reinterpret_cast<const bf16x8*>(ap + ks * 32);
#pragma unroll
        for (int nt = 0; nt < 3; ++nt) {
            int n = nt * 16 + (l & 15);
            bf16x8 bf = *reinterpret_cast<const bf16x8*>(
                &Bs[n * W2LD + ks * 32 + ((l >> 4) << 3)]);
            acc[nt] = __builtin_amdgcn_mfma_f32_16x16x32_bf16(af, bf, acc[nt], 0, 0, 0);
        }
    }

    const int c16 = l & 15;
    float bv[3];
    bool val[3];
#pragma unroll
    for (int nt = 0; nt < 3; ++nt) {
        int col = nt * 16 + c16;
        val[nt] = col < NCLASS;
        bv[nt] = val[nt] ? b2[col] : 0.f;
    }
#pragma unroll
    for (int r = 0; r < 4; ++r) {
        float lg[3];
        float m = -1e30f;
#pragma unroll
        for (int nt = 0; nt < 3; ++nt) {
            lg[nt] = acc[nt][r] + bv[nt];
            if (val[nt]) m = fmaxf(m, lg[nt]);
        }
#pragma unroll
        for (int off = 1; off < 16; off <<= 1) m = fmaxf(m, __shfl_xor(m, off));
        float s = 0.f;
#pragma unroll
        for (int nt = 0; nt < 3; ++nt)
            if (val[nt]) s += __expf(lg[nt] - m);
#pragma unroll
        for (int off = 1; off < 16; off <<= 1) s += __shfl_xor(s, off);
        float lse = __logf(s);
        int row = row0 + ((l >> 4) << 2) + r;
        if (row < N_NODES) {
#pragma unroll
            for (int nt = 0; nt < 3; ++nt)
                if (val[nt])
                    out[(size_t)row * NCLASS + nt * 16 + c16] = lg[nt] - m - lse;
        }
    }
}

// ---------------------------------------------------------------------------
// Fallback path (workspace too small for buckets)
// ---------------------------------------------------------------------------
__global__ __launch_bounds__(256) void k_agg_atomic(const bf16_t* __restrict__ support,
                                                    const int* __restrict__ src,
                                                    const int* __restrict__ dst,
                                                    const float* __restrict__ ew,
                                                    float* __restrict__ hf) {
    int e = blockIdx.x * 8 + (threadIdx.x >> 5);
    int l = threadIdx.x & 31;
    if (e >= N_EDGES) return;
    int s = src[e];
    int d = dst[e];
    float w = ew[e];
    const bf16_t* r = support + (size_t)s * NHID;
    float* hd = hf + (size_t)d * NHID;
    atomicAdd(&hd[l], w * (float)r[l]);
    atomicAdd(&hd[l + 32], w * (float)r[l + 32]);
    atomicAdd(&hd[l + 64], w * (float)r[l + 64]);
}

__global__ __launch_bounds__(256) void k_gemm2_fb(const float* __restrict__ hf,
                                                  const bf16_t* __restrict__ w2t,
                                                  const float* __restrict__ b2,
                                                  float* __restrict__ out) {
    __shared__ bf16_t hs[64][W2LD];
    __shared__ bf16_t Bs[48 * W2LD];
    const int tid = threadIdx.x;
#pragma unroll
    for (int i = tid; i < 48 * W2LD / 8; i += 256)
        *reinterpret_cast<uint4*>(Bs + i * 8) =
            *reinterpret_cast<const uint4*>(w2t + i * 8);
    const int row0 = blockIdx.x * 64;
    for (int i = tid; i < 64 * NHID; i += 256) {
        int r = i / NHID, c = i - r * NHID;
        int row = row0 + r;
        float v = (row < N_NODES) ? fmaxf(hf[(size_t)row * NHID + c], 0.f) : 0.f;
        hs[r][c] = (bf16_t)v;
    }
    __syncthreads();
    const int w = tid >> 6;
    const int l64 = tid & 63;
    const int r16 = l64 & 15;
    const int kq = l64 >> 4;
    f32x4 acc[3];
#pragma unroll
    for (int nt = 0; nt < 3; ++nt) acc[nt] = (f32x4){0.f, 0.f, 0.f, 0.f};
#pragma unroll
    for (int ks = 0; ks < 3; ++ks) {
        bf16x8 af = *reinterpret_cast<const bf16x8*>(&hs[w * 16 + r16][ks * 32 + (kq << 3)]);
#pragma unroll
        for (int nt = 0; nt < 3; ++nt) {
            int n = nt * 16 + r16;
            bf16x8 bf = *reinterpret_cast<const bf16x8*>(&Bs[n * W2LD + ks * 32 + (kq << 3)]);
            acc[nt] = __builtin_amdgcn_mfma_f32_16x16x32_bf16(af, bf, acc[nt], 0, 0, 0);
        }
    }
    float bv[3];
    bool val[3];
#pragma unroll
    for (int nt = 0; nt < 3; ++nt) {
        int col = nt * 16 + r16;
        val[nt] = col < NCLASS;
        bv[nt] = val[nt] ? b2[col] : 0.f;
    }
#pragma unroll
    for (int r = 0; r < 4; ++r) {
        float lg[3];
        float m = -1e30f;
#pragma unroll
        for (int nt = 0; nt < 3; ++nt) {
            lg[nt] = acc[nt][r] + bv[nt];
            if (val[nt]) m = fmaxf(m, lg[nt]);
        }
#pragma unroll
        for (int off = 1; off < 16; off <<= 1) m = fmaxf(m, __shfl_xor(m, off));
        float s = 0.f;
#pragma unroll
        for (int nt = 0; nt < 3; ++nt)
            if (val[nt]) s += __expf(lg[nt] - m);
#pragma unroll
        for (int off = 1; off < 16; off <<= 1) s += __shfl_xor(s, off);
        float lse = __logf(s);
        int row = row0 + w * 16 + kq * 4 + r;
        if (row < N_NODES) {
#pragma unroll
            for (int nt = 0; nt < 3; ++nt)
                if (val[nt])
                    out[(size_t)row * NCLASS + nt * 16 + r16] = lg[nt] - m - lse;
        }
    }
}

// ---------------------------------------------------------------------------
extern "C" void kernel_launch(void* const* d_in, const int* in_sizes, int n_in,
                              void* d_out, int out_size, void* d_ws, size_t ws_size,
                              hipStream_t stream) {
    const float* x  = (const float*)d_in[0];
    const int* ei   = (const int*)d_in[1];
    const float* ew = (const float*)d_in[2];
    const float* W1 = (const float*)d_in[3];
    const float* b1 = (const float*)d_in[4];
    const float* W2 = (const float*)d_in[5];
    const float* b2 = (const float*)d_in[6];
    float* out = (float*)d_out;
    const int* src = ei;
    const int* dst = ei + N_EDGES;

    char* ws = (char*)d_ws;
    size_t off = 0;
    auto alloc = [&](size_t bytes) -> void* {
        void* p = ws + off;
        off = (off + bytes + 255) & ~(size_t)255;
        return p;
    };
    bf16_t* support = (bf16_t*)alloc((size_t)N_NODES * NHID * 2);
    bf16_t* h       = (bf16_t*)alloc((size_t)N_NODES * NHID * 2);
    bf16_t* w1t     = (bf16_t*)alloc((size_t)NHID * NFEAT * 2);
    bf16_t* w2t     = (bf16_t*)alloc((size_t)48 * W2LD * 2);
    int* cnt        = (int*)alloc((size_t)N_NODES * 4);
    unsigned int* buck = (unsigned int*)alloc((size_t)N_NODES * BUCKET * 4);
    const bool fits = (off <= ws_size);
    float* hf       = (float*)alloc((size_t)N_NODES * NHID * 4);  // fallback only

    k_prep<<<PREP_BLOCKS, 256, 0, stream>>>(W1, W2, w1t, w2t, cnt);

    if (fits) {
        k_gemm1_scatter<<<GEMM1_BLOCKS + SCATTER_BLOCKS, 256, 0, stream>>>(
            x, w1t, b1, support, src, dst, ew, cnt, buck);
        k_agg<<<(N_NODES + 7) / 8, 256, 0, stream>>>(support, cnt, buck, h);
        k_gemm2_mfma<<<(N_NODES + 63) / 64, 256, 0, stream>>>(h, w2t, b2, out);
    } else {
        k_gemm1_scatter<<<GEMM1_BLOCKS, 256, 0, stream>>>(
            x, w1t, b1, support, src, dst, ew, cnt, buck);
        k_zero<<<(N_NODES * NHID + 255) / 256, 256, 0, stream>>>((int*)hf, N_NODES * NHID);
        k_agg_atomic<<<(N_EDGES + 7) / 8, 256, 0, stream>>>(support, src, dst, ew, hf);
        k_gemm2_fb<<<(N_NODES + 63) / 64, 256, 0, stream>>>(hf, w2t, b2, out);
    }
}

// Round 15
// 99.996 us; speedup vs baseline: 1.0823x; 1.0028x over previous
//
#include <hip/hip_runtime.h>
#include <hip/hip_fp16.h>
#include <math.h>

static constexpr int N_NODES = 50000;
static constexpr int N_EDGES = 800000;
static constexpr int NFEAT = 512;
static constexpr int NHID = 96;
static constexpr int NCLASS = 40;
static constexpr int PREP_BLOCKS = 196;        // 196*256 = 50176 >= N_NODES
static constexpr int GEMM1_BLOCKS = (N_NODES + 63) / 64;   // 782 (R10-proven)
static constexpr int BUCKET = 64;              // max degree capacity (P(deg>63)~1e-13)
static constexpr int W2LD = 104;               // padded row stride (bf16)
// XCD-partitioned scatter geometry (R10-proven)
static constexpr int SC_GROUPS = 8;
static constexpr int SC_RANGE = N_NODES / SC_GROUPS;       // 6250
static constexpr int SC_CHUNK = 2048;
static constexpr int SC_CHUNKS = (N_EDGES + SC_CHUNK - 1) / SC_CHUNK;  // 391
static constexpr int SCATTER_BLOCKS = SC_GROUPS * SC_CHUNKS;           // 3128
static constexpr int AGG_BLOCKS = N_NODES / 16;            // 3125 (50000 = 16*3125)

typedef __bf16 bf16_t;
typedef __attribute__((ext_vector_type(8))) __bf16 bf16x8;
typedef __attribute__((ext_vector_type(4))) float f32x4;

// ---------------------------------------------------------------------------
// Zero-fill (fallback path only)
// ---------------------------------------------------------------------------
__global__ __launch_bounds__(256) void k_zero(int* __restrict__ p, int n) {
    int i = blockIdx.x * 256 + threadIdx.x;
    if (i < n) p[i] = 0;
}

// ---------------------------------------------------------------------------
// Prep (fused): W1 -> w1t bf16 transposed; W2 -> w2t bf16 transposed+padded;
// zero cnt[50000] (bucket cursors / degree counts).
// ---------------------------------------------------------------------------
__global__ __launch_bounds__(256) void k_prep(const float* __restrict__ W1,
                                              const float* __restrict__ W2,
                                              bf16_t* __restrict__ w1t,
                                              bf16_t* __restrict__ w2t,
                                              int* __restrict__ cnt) {
    int e = blockIdx.x * 256 + threadIdx.x;
    if (e < N_NODES) cnt[e] = 0;
    if (e < NFEAT * NHID) {
        int k = e / NHID;
        int n = e - k * NHID;
        w1t[(size_t)n * NFEAT + k] = (bf16_t)W1[e];
    }
    if (e < 48 * NHID) {
        int n = e / NHID;
        int k = e - n * NHID;
        w2t[n * W2LD + k] = (n < NCLASS) ? (bf16_t)W2[k * NCLASS + n] : (bf16_t)0.f;
    }
}

// ---------------------------------------------------------------------------
// FUSED GEMM1 (bf16 MFMA) + XCD-partitioned scatter -- EXACT R10 body
// (proven best across R9/R11/R12/R13 probes).
// ---------------------------------------------------------------------------
static __device__ inline bf16x8 cvt8(float4 u, float4 v) {
    bf16x8 r;
    r[0] = (bf16_t)u.x; r[1] = (bf16_t)u.y; r[2] = (bf16_t)u.z; r[3] = (bf16_t)u.w;
    r[4] = (bf16_t)v.x; r[5] = (bf16_t)v.y; r[6] = (bf16_t)v.z; r[7] = (bf16_t)v.w;
    return r;
}

__global__ __launch_bounds__(256) void k_gemm1_scatter(
        const float* __restrict__ x, const bf16_t* __restrict__ w1t,
        const float* __restrict__ b1, bf16_t* __restrict__ support,
        const int* __restrict__ src, const int* __restrict__ dst,
        const float* __restrict__ ew, int* __restrict__ cnt,
        unsigned int* __restrict__ buck) {
    __shared__ bf16_t Bs[NHID * 64];  // [n][k] 96x64 bf16 = 12KB, XOR-swizzled
    const int tid = threadIdx.x;

    if (blockIdx.x >= GEMM1_BLOCKS) {  // scatter path (block-uniform branch)
        const int si = blockIdx.x - GEMM1_BLOCKS;
        const int g = si & 7;           // dst-range group == XCD-coherent set
        const int c = si >> 3;          // edge chunk
        const int lo = g * SC_RANGE;
        const int hi = lo + SC_RANGE;
        const int base = c * SC_CHUNK;
#pragma unroll
        for (int t = 0; t < SC_CHUNK / 256; ++t) {
            int i = base + t * 256 + tid;
            if (i < N_EDGES) {
                int d = dst[i];
                if (d >= lo && d < hi) {
                    int rank = atomicAdd(&cnt[d], 1);
                    if (rank < BUCKET) {
                        __half hh = __float2half(ew[i]);
                        unsigned short us = *reinterpret_cast<unsigned short*>(&hh);
                        buck[(size_t)d * BUCKET + rank] =
                            ((unsigned int)src[i] << 16) | (unsigned int)us;
                    }
                }
            }
        }
        return;
    }

    const int w = tid >> 6;
    const int l = tid & 63;
    const int row0 = blockIdx.x * 64;

    int arow = row0 + w * 16 + (l & 15);
    if (arow > N_NODES - 1) arow = N_NODES - 1;  // clamp: dup loads, masked store
    const float* ap = x + (size_t)arow * NFEAT + ((l >> 4) << 3);

    f32x4 acc[6];
#pragma unroll
    for (int nt = 0; nt < 6; ++nt) acc[nt] = (f32x4){0.f, 0.f, 0.f, 0.f};

    for (int kt = 0; kt < NFEAT; kt += 64) {
        float4 a0 = *reinterpret_cast<const float4*>(ap + kt);
        float4 a1 = *reinterpret_cast<const float4*>(ap + kt + 4);
        float4 a2 = *reinterpret_cast<const float4*>(ap + kt + 32);
        float4 a3 = *reinterpret_cast<const float4*>(ap + kt + 36);

        __syncthreads();
#pragma unroll
        for (int p = 0; p < 3; ++p) {
            int idx = tid + p * 256;
            int n = idx >> 3;
            int c4 = idx & 7;
            uint4 v = *reinterpret_cast<const uint4*>(w1t + (size_t)n * NFEAT + kt + c4 * 8);
            int ba = (n * 128 + c4 * 16) ^ ((n & 7) << 4);
            *reinterpret_cast<uint4*>(reinterpret_cast<char*>(Bs) + ba) = v;
        }
        __syncthreads();

        bf16x8 af0 = cvt8(a0, a1);
        bf16x8 af1 = cvt8(a2, a3);
        const int koff = (l >> 4) << 4;
#pragma unroll
        for (int nt = 0; nt < 6; ++nt) {
            int n = nt * 16 + (l & 15);
            int ba0 = (n * 128 + koff) ^ ((n & 7) << 4);
            int ba1 = (n * 128 + 64 + koff) ^ ((n & 7) << 4);
            bf16x8 bf0 = *reinterpret_cast<const bf16x8*>(reinterpret_cast<const char*>(Bs) + ba0);
            bf16x8 bf1 = *reinterpret_cast<const bf16x8*>(reinterpret_cast<const char*>(Bs) + ba1);
            acc[nt] = __builtin_amdgcn_mfma_f32_16x16x32_bf16(af0, bf0, acc[nt], 0, 0, 0);
            acc[nt] = __builtin_amdgcn_mfma_f32_16x16x32_bf16(af1, bf1, acc[nt], 0, 0, 0);
        }
    }

    // Epilogue: C layout col=lane&15, row=(lane>>4)*4+reg (m89-verified)
    const int col16 = l & 15;
    const int rq = l >> 4;
#pragma unroll
    for (int nt = 0; nt < 6; ++nt) {
        int col = nt * 16 + col16;
        float bv = b1[col];
#pragma unroll
        for (int r = 0; r < 4; ++r) {
            int row = row0 + w * 16 + rq * 4 + r;
            if (row < N_NODES)
                support[(size_t)row * NHID + col] = (bf16_t)(acc[nt][r] + bv);
        }
    }
}

// ---------------------------------------------------------------------------
// FUSED aggregate + ReLU + GEMM2 + log_softmax.
// Block = 512 threads = 16 groups x 1 node each (SAME node-level parallelism
// as the proven k_agg -- avoids R5's 8-nodes-serial mistake). h-tile [16][104]
// stays in LDS (saves the 19.2MB h global round-trip + one dispatch). After
// one barrier, wave 0 runs the PROVEN gemm2_fb MFMA+softmax body (w=0) for
// the block's 16 rows; idle-wave cost hides across 3125 blocks.
// ---------------------------------------------------------------------------
static __device__ inline float dec_w(unsigned int v) {
    unsigned short us = (unsigned short)(v & 0xffffu);
    __half hh = *reinterpret_cast<__half*>(&us);
    return __half2float(hh);
}

__global__ __launch_bounds__(512) void k_agg_gemm2(const bf16_t* __restrict__ support,
                                                   const int* __restrict__ cnt,
                                                   const unsigned int* __restrict__ buck,
                                                   const bf16_t* __restrict__ w2t,
                                                   const float* __restrict__ b2,
                                                   float* __restrict__ out) {
    __shared__ bf16_t hs[16][W2LD];
    __shared__ bf16_t Bs[48 * W2LD];
    const int tid = threadIdx.x;
    // stage w2t once per block (512 threads, 624 uint4)
    for (int i = tid; i < 48 * W2LD / 8; i += 512)
        *reinterpret_cast<uint4*>(Bs + i * 8) =
            *reinterpret_cast<const uint4*>(w2t + i * 8);

    const int gi = tid >> 5;   // 0..15: node group
    const int l = tid & 31;
    const int g = blockIdx.x * 16 + gi;   // 50000 = 16*3125, always in range

    // ---- aggregate (R14-proven 8-edge unroll, 24 gathers in flight) ----
    int deg = cnt[g];
    if (deg > BUCKET) deg = BUCKET;
    const unsigned int* bk = buck + (size_t)g * BUCKET;
    float a0 = 0.f, a1 = 0.f, a2 = 0.f;
    int e = 0;
    for (; e + 8 <= deg; e += 8) {
        uint4 q = *reinterpret_cast<const uint4*>(bk + e);
        uint4 p = *reinterpret_cast<const uint4*>(bk + e + 4);
        const bf16_t* r0 = support + (size_t)(q.x >> 16) * NHID;
        const bf16_t* r1 = support + (size_t)(q.y >> 16) * NHID;
        const bf16_t* r2 = support + (size_t)(q.z >> 16) * NHID;
        const bf16_t* r3 = support + (size_t)(q.w >> 16) * NHID;
        const bf16_t* r4 = support + (size_t)(p.x >> 16) * NHID;
        const bf16_t* r5 = support + (size_t)(p.y >> 16) * NHID;
        const bf16_t* r6 = support + (size_t)(p.z >> 16) * NHID;
        const bf16_t* r7 = support + (size_t)(p.w >> 16) * NHID;
        float w0 = dec_w(q.x), w1 = dec_w(q.y), w2 = dec_w(q.z), w3 = dec_w(q.w);
        float w4 = dec_w(p.x), w5 = dec_w(p.y), w6 = dec_w(p.z), w7 = dec_w(p.w);
        float v00 = (float)r0[l], v01 = (float)r0[l + 32], v02 = (float)r0[l + 64];
        float v10 = (float)r1[l], v11 = (float)r1[l + 32], v12 = (float)r1[l + 64];
        float v20 = (float)r2[l], v21 = (float)r2[l + 32], v22 = (float)r2[l + 64];
        float v30 = (float)r3[l], v31 = (float)r3[l + 32], v32 = (float)r3[l + 64];
        float v40 = (float)r4[l], v41 = (float)r4[l + 32], v42 = (float)r4[l + 64];
        float v50 = (float)r5[l], v51 = (float)r5[l + 32], v52 = (float)r5[l + 64];
        float v60 = (float)r6[l], v61 = (float)r6[l + 32], v62 = (float)r6[l + 64];
        float v70 = (float)r7[l], v71 = (float)r7[l + 32], v72 = (float)r7[l + 64];
        a0 = fmaf(w0, v00, a0); a1 = fmaf(w0, v01, a1); a2 = fmaf(w0, v02, a2);
        a0 = fmaf(w1, v10, a0); a1 = fmaf(w1, v11, a1); a2 = fmaf(w1, v12, a2);
        a0 = fmaf(w2, v20, a0); a1 = fmaf(w2, v21, a1); a2 = fmaf(w2, v22, a2);
        a0 = fmaf(w3, v30, a0); a1 = fmaf(w3, v31, a1); a2 = fmaf(w3, v32, a2);
        a0 = fmaf(w4, v40, a0); a1 = fmaf(w4, v41, a1); a2 = fmaf(w4, v42, a2);
        a0 = fmaf(w5, v50, a0); a1 = fmaf(w5, v51, a1); a2 = fmaf(w5, v52, a2);
        a0 = fmaf(w6, v60, a0); a1 = fmaf(w6, v61, a1); a2 = fmaf(w6, v62, a2);
        a0 = fmaf(w7, v70, a0); a1 = fmaf(w7, v71, a1); a2 = fmaf(w7, v72, a2);
    }
    for (; e + 4 <= deg; e += 4) {
        uint4 q = *reinterpret_cast<const uint4*>(bk + e);
        const bf16_t* r0 = support + (size_t)(q.x >> 16) * NHID;
        const bf16_t* r1 = support + (size_t)(q.y >> 16) * NHID;
        const bf16_t* r2 = support + (size_t)(q.z >> 16) * NHID;
        const bf16_t* r3 = support + (size_t)(q.w >> 16) * NHID;
        float w0 = dec_w(q.x), w1 = dec_w(q.y), w2 = dec_w(q.z), w3 = dec_w(q.w);
        float v00 = (float)r0[l], v01 = (float)r0[l + 32], v02 = (float)r0[l + 64];
        float v10 = (float)r1[l], v11 = (float)r1[l + 32], v12 = (float)r1[l + 64];
        float v20 = (float)r2[l], v21 = (float)r2[l + 32], v22 = (float)r2[l + 64];
        float v30 = (float)r3[l], v31 = (float)r3[l + 32], v32 = (float)r3[l + 64];
        a0 = fmaf(w0, v00, a0); a1 = fmaf(w0, v01, a1); a2 = fmaf(w0, v02, a2);
        a0 = fmaf(w1, v10, a0); a1 = fmaf(w1, v11, a1); a2 = fmaf(w1, v12, a2);
        a0 = fmaf(w2, v20, a0); a1 = fmaf(w2, v21, a1); a2 = fmaf(w2, v22, a2);
        a0 = fmaf(w3, v30, a0); a1 = fmaf(w3, v31, a1); a2 = fmaf(w3, v32, a2);
    }
    for (; e < deg; ++e) {
        unsigned int v = bk[e];
        const bf16_t* r = support + (size_t)(v >> 16) * NHID;
        float wv = dec_w(v);
        a0 = fmaf(wv, (float)r[l], a0);
        a1 = fmaf(wv, (float)r[l + 32], a1);
        a2 = fmaf(wv, (float)r[l + 64], a2);
    }
    hs[gi][l]      = (bf16_t)fmaxf(a0, 0.f);
    hs[gi][l + 32] = (bf16_t)fmaxf(a1, 0.f);
    hs[gi][l + 64] = (bf16_t)fmaxf(a2, 0.f);
    __syncthreads();  // hs + Bs ready

    // ---- gemm2 + log_softmax by wave 0 (proven gemm2_fb body, w=0) ----
    if (tid < 64) {
        const int l64 = tid;
        const int r16 = l64 & 15;
        const int kq = l64 >> 4;
        f32x4 acc[3];
#pragma unroll
        for (int nt = 0; nt < 3; ++nt) acc[nt] = (f32x4){0.f, 0.f, 0.f, 0.f};
#pragma unroll
        for (int ks = 0; ks < 3; ++ks) {
            bf16x8 af = *reinterpret_cast<const bf16x8*>(&hs[r16][ks * 32 + (kq << 3)]);
#pragma unroll
            for (int nt = 0; nt < 3; ++nt) {
                int n = nt * 16 + r16;
                bf16x8 bf = *reinterpret_cast<const bf16x8*>(&Bs[n * W2LD + ks * 32 + (kq << 3)]);
                acc[nt] = __builtin_amdgcn_mfma_f32_16x16x32_bf16(af, bf, acc[nt], 0, 0, 0);
            }
        }
        float bv[3];
        bool val[3];
#pragma unroll
        for (int nt = 0; nt < 3; ++nt) {
            int col = nt * 16 + r16;
            val[nt] = col < NCLASS;
            bv[nt] = val[nt] ? b2[col] : 0.f;
        }
#pragma unroll
        for (int r = 0; r < 4; ++r) {
            float lg[3];
            float m = -1e30f;
#pragma unroll
            for (int nt = 0; nt < 3; ++nt) {
                lg[nt] = acc[nt][r] + bv[nt];
                if (val[nt]) m = fmaxf(m, lg[nt]);
            }
#pragma unroll
            for (int off = 1; off < 16; off <<= 1) m = fmaxf(m, __shfl_xor(m, off));
            float s = 0.f;
#pragma unroll
            for (int nt = 0; nt < 3; ++nt)
                if (val[nt]) s += __expf(lg[nt] - m);
#pragma unroll
            for (int off = 1; off < 16; off <<= 1) s += __shfl_xor(s, off);
            float lse = __logf(s);
            int row = blockIdx.x * 16 + kq * 4 + r;
#pragma unroll
            for (int nt = 0; nt < 3; ++nt)
                if (val[nt])
                    out[(size_t)row * NCLASS + nt * 16 + r16] = lg[nt] - m - lse;
        }
    }
}

// ---------------------------------------------------------------------------
// Fallback path (workspace too small for buckets)
// ---------------------------------------------------------------------------
__global__ __launch_bounds__(256) void k_agg_atomic(const bf16_t* __restrict__ support,
                                                    const int* __restrict__ src,
                                                    const int* __restrict__ dst,
                                                    const float* __restrict__ ew,
                                                    float* __restrict__ hf) {
    int e = blockIdx.x * 8 + (threadIdx.x >> 5);
    int l = threadIdx.x & 31;
    if (e >= N_EDGES) return;
    int s = src[e];
    int d = dst[e];
    float w = ew[e];
    const bf16_t* r = support + (size_t)s * NHID;
    float* hd = hf + (size_t)d * NHID;
    atomicAdd(&hd[l], w * (float)r[l]);
    atomicAdd(&hd[l + 32], w * (float)r[l + 32]);
    atomicAdd(&hd[l + 64], w * (float)r[l + 64]);
}

__global__ __launch_bounds__(256) void k_gemm2_fb(const float* __restrict__ hf,
                                                  const bf16_t* __restrict__ w2t,
                                                  const float* __restrict__ b2,
                                                  float* __restrict__ out) {
    __shared__ bf16_t hs[64][W2LD];
    __shared__ bf16_t Bs[48 * W2LD];
    const int tid = threadIdx.x;
#pragma unroll
    for (int i = tid; i < 48 * W2LD / 8; i += 256)
        *reinterpret_cast<uint4*>(Bs + i * 8) =
            *reinterpret_cast<const uint4*>(w2t + i * 8);
    const int row0 = blockIdx.x * 64;
    for (int i = tid; i < 64 * NHID; i += 256) {
        int r = i / NHID, c = i - r * NHID;
        int row = row0 + r;
        float v = (row < N_NODES) ? fmaxf(hf[(size_t)row * NHID + c], 0.f) : 0.f;
        hs[r][c] = (bf16_t)v;
    }
    __syncthreads();
    const int w = tid >> 6;
    const int l64 = tid & 63;
    const int r16 = l64 & 15;
    const int kq = l64 >> 4;
    f32x4 acc[3];
#pragma unroll
    for (int nt = 0; nt < 3; ++nt) acc[nt] = (f32x4){0.f, 0.f, 0.f, 0.f};
#pragma unroll
    for (int ks = 0; ks < 3; ++ks) {
        bf16x8 af = *reinterpret_cast<const bf16x8*>(&hs[w * 16 + r16][ks * 32 + (kq << 3)]);
#pragma unroll
        for (int nt = 0; nt < 3; ++nt) {
            int n = nt * 16 + r16;
            bf16x8 bf = *reinterpret_cast<const bf16x8*>(&Bs[n * W2LD + ks * 32 + (kq << 3)]);
            acc[nt] = __builtin_amdgcn_mfma_f32_16x16x32_bf16(af, bf, acc[nt], 0, 0, 0);
        }
    }
    float bv[3];
    bool val[3];
#pragma unroll
    for (int nt = 0; nt < 3; ++nt) {
        int col = nt * 16 + r16;
        val[nt] = col < NCLASS;
        bv[nt] = val[nt] ? b2[col] : 0.f;
    }
#pragma unroll
    for (int r = 0; r < 4; ++r) {
        float lg[3];
        float m = -1e30f;
#pragma unroll
        for (int nt = 0; nt < 3; ++nt) {
            lg[nt] = acc[nt][r] + bv[nt];
            if (val[nt]) m = fmaxf(m, lg[nt]);
        }
#pragma unroll
        for (int off = 1; off < 16; off <<= 1) m = fmaxf(m, __shfl_xor(m, off));
        float s = 0.f;
#pragma unroll
        for (int nt = 0; nt < 3; ++nt)
            if (val[nt]) s += __expf(lg[nt] - m);
#pragma unroll
        for (int off = 1; off < 16; off <<= 1) s += __shfl_xor(s, off);
        float lse = __logf(s);
        int row = row0 + w * 16 + kq * 4 + r;
        if (row < N_NODES) {
#pragma unroll
            for (int nt = 0; nt < 3; ++nt)
                if (val[nt])
                    out[(size_t)row * NCLASS + nt * 16 + r16] = lg[nt] - m - lse;
        }
    }
}

// ---------------------------------------------------------------------------
extern "C" void kernel_launch(void* const* d_in, const int* in_sizes, int n_in,
                              void* d_out, int out_size, void* d_ws, size_t ws_size,
                              hipStream_t stream) {
    const float* x  = (const float*)d_in[0];
    const int* ei   = (const int*)d_in[1];
    const float* ew = (const float*)d_in[2];
    const float* W1 = (const float*)d_in[3];
    const float* b1 = (const float*)d_in[4];
    const float* W2 = (const float*)d_in[5];
    const float* b2 = (const float*)d_in[6];
    float* out = (float*)d_out;
    const int* src = ei;
    const int* dst = ei + N_EDGES;

    char* ws = (char*)d_ws;
    size_t off = 0;
    auto alloc = [&](size_t bytes) -> void* {
        void* p = ws + off;
        off = (off + bytes + 255) & ~(size_t)255;
        return p;
    };
    bf16_t* support = (bf16_t*)alloc((size_t)N_NODES * NHID * 2);
    bf16_t* w1t     = (bf16_t*)alloc((size_t)NHID * NFEAT * 2);
    bf16_t* w2t     = (bf16_t*)alloc((size_t)48 * W2LD * 2);
    int* cnt        = (int*)alloc((size_t)N_NODES * 4);
    unsigned int* buck = (unsigned int*)alloc((size_t)N_NODES * BUCKET * 4);
    const bool fits = (off <= ws_size);
    float* hf       = (float*)alloc((size_t)N_NODES * NHID * 4);  // fallback only

    k_prep<<<PREP_BLOCKS, 256, 0, stream>>>(W1, W2, w1t, w2t, cnt);

    if (fits) {
        k_gemm1_scatter<<<GEMM1_BLOCKS + SCATTER_BLOCKS, 256, 0, stream>>>(
            x, w1t, b1, support, src, dst, ew, cnt, buck);
        k_agg_gemm2<<<AGG_BLOCKS, 512, 0, stream>>>(support, cnt, buck, w2t, b2, out);
    } else {
        k_gemm1_scatter<<<GEMM1_BLOCKS, 256, 0, stream>>>(
            x, w1t, b1, support, src, dst, ew, cnt, buck);
        k_zero<<<(N_NODES * NHID + 255) / 256, 256, 0, stream>>>((int*)hf, N_NODES * NHID);
        k_agg_atomic<<<(N_EDGES + 7) / 8, 256, 0, stream>>>(support, src, dst, ew, hf);
        k_gemm2_fb<<<(N_NODES + 63) / 64, 256, 0, stream>>>(hf, w2t, b2, out);
    }
}